// Round 6
// baseline (175.266 us; speedup 1.0000x reference)
//
#include <hip/hip_runtime.h>
#include <stdint.h>

#define TWF 0.2f
#define NPTS 16384

typedef __attribute__((ext_vector_type(8))) short short8;
typedef __attribute__((ext_vector_type(4))) float floatx4;

__device__ __forceinline__ short f2bf(float f){
  unsigned u = __float_as_uint(f);
  u += 0x7fff + ((u >> 16) & 1);           // round-to-nearest-even
  return (short)(u >> 16);
}
__device__ __forceinline__ float bf2f(short s){
  return __uint_as_float(((unsigned)(unsigned short)s) << 16);
}
// tanh(x) = 1 - 2/(exp2(2*log2e*x)+1); exact at +/-inf
__device__ __forceinline__ float fast_tanh(float x){
  float e = __builtin_amdgcn_exp2f(x * 2.885390082f);
  float r = __builtin_amdgcn_rcpf(e + 1.f);
  return fmaf(-2.f, r, 1.f);
}
// cos(pi*t) via v_cos (revolutions)
__device__ __forceinline__ float cospi_t(float t){
  return __builtin_amdgcn_cosf(t * 0.5f);
}
// swizzled LDS index (in shorts) for h[m][j], m in [0,64), j in [0,256)
__device__ __forceinline__ int swz(int m, int j){
  return m * 256 + ((((j >> 3) ^ (m & 7)) << 3) | (j & 7));
}

// ws layout (bytes):
//   [0, 4M)            : bf16-swizzled W1/W2
//   [4M, 4M+4K)        : cnt8[16][256]  (count of active pts per (k, 64-pt segment))
//   [4M+4K, 5M+4K)     : ilist[16][seg*64+local]
//   [5M+4K, 6M+4K)     : wlist[16][seg*64+local]
#define WS_W      0
#define WS_CNT    (4u<<20)
#define WS_ILIST  ((4u<<20) + 4096u)
#define WS_WLIST  ((5u<<20) + 4096u)

// Fused prep: blocks [0,1024) convert W1/W2 to bf16 B-fragment order;
// blocks [1024,1088) zero `out` and build per-(k,segment) compacted lists.
// NO atomics, NO barriers: each wave owns one 64-point segment exclusively.
__global__ __launch_bounds__(256) void prep_fused(
    const float* __restrict__ W1, const float* __restrict__ W2,
    const float* __restrict__ x,  const float* __restrict__ xmins,
    const float* __restrict__ xmaxs, short* __restrict__ dst,
    unsigned char* __restrict__ cnt8, int* __restrict__ ilist,
    float* __restrict__ wlist, float* __restrict__ out){
  if (blockIdx.x < 1024){
    int gid = blockIdx.x * 256 + threadIdx.x;   // 2*16*8*16*64 = 262144 total
    int lane = gid & 63; int rest = gid >> 6;
    int jt = rest & 15; rest >>= 4;
    int ks = rest & 7;  rest >>= 3;
    int k  = rest & 15; int mat = rest >> 4;
    const float* W = mat ? W2 : W1;
    int j   = jt * 16 + (lane & 15);
    int kk0 = ks * 32 + (lane >> 4) * 8;
    short8 v;
    #pragma unroll
    for (int jj = 0; jj < 8; jj++)
      v[jj] = f2bf(W[k * 65536 + (kk0 + jj) * 256 + j]);
    *(short8*)(dst + (size_t)gid * 8) = v;
  } else {
    int bb   = blockIdx.x - 1024;
    int t    = threadIdx.x;
    int lane = t & 63, wave = t >> 6;
    out[bb * 256 + t] = 0.f;                   // fold memset(out)
    int seg = bb * 4 + wave;                   // this wave's 64-point segment
    int pt  = seg * 64 + lane;
    float px = x[pt * 2 + 0], py = x[pt * 2 + 1];
    float wr[16]; float sum = 0.f;
    #pragma unroll
    for (int k = 0; k < 16; k++){
      float w = 1.f;
      #pragma unroll
      for (int d = 0; d < 2; d++){
        float xv = d ? py : px;
        float mn = xmins[k * 2 + d], mx = xmaxs[k * 2 + d];
        float tl = fminf(fmaxf((xv - (mn - TWF)) * (1.f / (2.f * TWF)), 0.f), 1.f);
        float tr = fminf(fmaxf(((mx + TWF) - xv) * (1.f / (2.f * TWF)), 0.f), 1.f);
        w *= 0.25f * (1.f - cospi_t(tl)) * (1.f - cospi_t(tr));
      }
      wr[k] = w; sum += w;
    }
    float inv = 1.f / (sum + 1e-9f);
    #pragma unroll 1
    for (int k = 0; k < 16; k++){
      bool act = wr[k] > 0.f;
      unsigned long long mask = __ballot(act);
      if (lane == 0) cnt8[k * 256 + seg] = (unsigned char)__popcll(mask);
      if (act){
        int pos = (int)__popcll(mask & ((1ull << lane) - 1ull));
        ilist[k * NPTS + seg * 64 + pos] = pt;
        wlist[k * NPTS + seg * 64 + pos] = wr[k] * inv;
      }
    }
  }
}

__global__ __launch_bounds__(256, 4) void fbpinn_main(
    const float* __restrict__ x,  const float* __restrict__ W0, const float* __restrict__ b0,
    const float* __restrict__ b1, const float* __restrict__ b2,
    const float* __restrict__ W3, const float* __restrict__ b3,
    const float* __restrict__ xmins, const float* __restrict__ xmaxs,
    const short* __restrict__ wsw, const unsigned int* __restrict__ cnt32,
    const int* __restrict__ ilist, const float* __restrict__ wlist,
    float* __restrict__ out)
{
  __shared__ short lds_h[64 * 256];   // 32 KB, swizzled bf16 h tile
  __shared__ float s_xn[64 * 2];
  __shared__ float s_win[64];
  __shared__ int   s_pidx[64];
  __shared__ float s_w3[256];
  __shared__ float s_w0[512];
  __shared__ int   s_tot[16];

  const int t    = threadIdx.x;
  const int lane = t & 63;
  const int wave = t >> 6;
  const int col  = lane & 15;
  const int quad = lane >> 4;

  // ---- once per block: per-k totals via wave reduction over packed counts ----
  if (t < 64){
    #pragma unroll
    for (int k = 0; k < 16; k++){
      unsigned p = cnt32[k * 64 + t];     // 4 segment counts packed as bytes
      int s4 = (int)((p & 255u) + ((p >> 8) & 255u) + ((p >> 16) & 255u) + (p >> 24));
      #pragma unroll
      for (int d = 1; d < 64; d <<= 1) s4 += __shfl_xor(s4, d);
      if (t == 0) s_tot[k] = s4;
    }
  }
  __syncthreads();

  int tb[17]; tb[0] = 0;
  #pragma unroll
  for (int kk = 0; kk < 16; kk++) tb[kk + 1] = tb[kk] + ((s_tot[kk] + 63) >> 6);
  const int total = tb[16];

  for (int tile = blockIdx.x; tile < total; tile += gridDim.x){
    int k = 0;
    #pragma unroll
    for (int kk = 1; kk < 16; kk++) k += (tile >= tb[kk]);
    const int base = (tile - tb[k]) * 64;
    const int cnt  = s_tot[k];

    __syncthreads();   // previous tile's reads done before s_* overwrite

    // ---- stage: locate compacted point via shfl scan + bisect, stage W0/W3 ----
    s_w3[t] = W3[k * 256 + t];
    s_w0[t] = W0[k * 512 + t];
    s_w0[256 + t] = W0[k * 512 + 256 + t];
    if (t < 64){
      unsigned pack = cnt32[k * 64 + t];
      int s4 = (int)((pack & 255u) + ((pack >> 8) & 255u) + ((pack >> 16) & 255u) + (pack >> 24));
      int inc = s4;
      #pragma unroll
      for (int d = 1; d < 64; d <<= 1){
        int v = __shfl_up(inc, d);
        if (t >= d) inc += v;
      }
      int excl = inc - s4;
      int g = base + t;
      bool valid = g < cnt;
      int gg = valid ? g : 0;
      int lo = 0;
      #pragma unroll
      for (int d = 32; d >= 1; d >>= 1){
        int cand = lo + d;
        int e = __shfl(excl, cand & 63);
        if (cand < 64 && e <= gg) lo = cand;
      }
      int e_lo = __shfl(excl, lo);
      unsigned p_lo = (unsigned)__shfl((int)pack, lo);
      int rem = gg - e_lo;
      int b0v = (int)(p_lo & 255u), b1v = (int)((p_lo >> 8) & 255u), b2v = (int)((p_lo >> 16) & 255u);
      int r = 0;
      if (rem >= b0v){ rem -= b0v; r = 1;
        if (rem >= b1v){ rem -= b1v; r = 2;
          if (rem >= b2v){ rem -= b2v; r = 3; } } }
      int idx = k * NPTS + (lo * 4 + r) * 64 + rem;
      int pidx = valid ? ilist[idx] : 0;
      float w  = valid ? wlist[idx] : 0.f;
      s_pidx[t] = pidx;
      s_win[t]  = w;
      float px = x[pidx * 2 + 0], py = x[pidx * 2 + 1];
      float cx = (xmins[k * 2 + 0] + xmaxs[k * 2 + 0]) * 0.5f;
      float cy = (xmins[k * 2 + 1] + xmaxs[k * 2 + 1]) * 0.5f;
      float sx = fmaxf((xmaxs[k * 2 + 0] - xmins[k * 2 + 0]) * 0.5f, 1e-9f);
      float sy = fmaxf((xmaxs[k * 2 + 1] - xmins[k * 2 + 1]) * 0.5f, 1e-9f);
      s_xn[t * 2 + 0] = (px - cx) / sx;
      s_xn[t * 2 + 1] = (py - cy) / sy;
    }
    __syncthreads();

    // ---- layer 0 (D=2 -> 256) as one MFMA K-step (K padded 2->32) ----
    {
      short8 bfr[4], afr[4];
      #pragma unroll
      for (int jtl = 0; jtl < 4; jtl++){
        int j = (wave * 4 + jtl) * 16 + col;
        short8 b;
        #pragma unroll
        for (int i = 0; i < 8; i++) b[i] = 0;
        b[0] = (quad == 0) ? f2bf(s_w0[j])       : (short)0;
        b[1] = (quad == 0) ? f2bf(s_w0[256 + j]) : (short)0;
        bfr[jtl] = b;
      }
      #pragma unroll
      for (int mt = 0; mt < 4; mt++){
        int m = mt * 16 + col;
        short8 a;
        #pragma unroll
        for (int i = 0; i < 8; i++) a[i] = 0;
        a[0] = (quad == 0) ? f2bf(s_xn[m * 2 + 0]) : (short)0;
        a[1] = (quad == 0) ? f2bf(s_xn[m * 2 + 1]) : (short)0;
        afr[mt] = a;
      }
      floatx4 acc[4][4];
      #pragma unroll
      for (int a = 0; a < 4; a++)
        #pragma unroll
        for (int b = 0; b < 4; b++)
          acc[a][b] = (floatx4){0.f, 0.f, 0.f, 0.f};
      #pragma unroll
      for (int mt = 0; mt < 4; mt++)
        #pragma unroll
        for (int jtl = 0; jtl < 4; jtl++)
          acc[mt][jtl] = __builtin_amdgcn_mfma_f32_16x16x32_bf16(afr[mt], bfr[jtl], acc[mt][jtl], 0, 0, 0);
      #pragma unroll
      for (int jtl = 0; jtl < 4; jtl++){
        int j = (wave * 4 + jtl) * 16 + col;
        float bb = b0[k * 256 + j];
        #pragma unroll
        for (int mt = 0; mt < 4; mt++){
          #pragma unroll
          for (int r = 0; r < 4; r++){
            int m = mt * 16 + quad * 4 + r;
            lds_h[swz(m, j)] = f2bf(fast_tanh(acc[mt][jtl][r] + bb));
          }
        }
      }
      __syncthreads();
    }

    // ---- layers 1,2: 64x256x256 bf16 MFMA; wave owns j-range [wave*64, +64) ----
    #pragma unroll 1
    for (int layer = 0; layer < 2; layer++){
      const short8* wb = (const short8*)(wsw + (size_t)layer * 1048576)
                         + ((size_t)(k * 8) * 16 + wave * 4) * 64 + lane;
      const float*  bp = layer ? b2 : b1;
      floatx4 acc[4][4];
      #pragma unroll
      for (int a = 0; a < 4; a++)
        #pragma unroll
        for (int b = 0; b < 4; b++)
          acc[a][b] = (floatx4){0.f, 0.f, 0.f, 0.f};

      short8 bcur[4];
      #pragma unroll
      for (int jtl = 0; jtl < 4; jtl++) bcur[jtl] = wb[jtl * 64];

      #pragma unroll
      for (int ks = 0; ks < 8; ks++){
        short8 bnxt[4];
        if (ks < 7){
          #pragma unroll
          for (int jtl = 0; jtl < 4; jtl++)
            bnxt[jtl] = wb[(ks + 1) * 1024 + jtl * 64];   // prefetch next K-step
        }
        short8 afr[4];
        #pragma unroll
        for (int mt = 0; mt < 4; mt++){
          int m   = mt * 16 + col;                 // A: m = lane&15
          int pos = (ks * 4 + quad) ^ (m & 7);     // A: k-chunk = quad
          afr[mt] = *(const short8*)&lds_h[m * 256 + pos * 8];
        }
        #pragma unroll
        for (int mt = 0; mt < 4; mt++)
          #pragma unroll
          for (int jtl = 0; jtl < 4; jtl++)
            acc[mt][jtl] = __builtin_amdgcn_mfma_f32_16x16x32_bf16(afr[mt], bcur[jtl], acc[mt][jtl], 0, 0, 0);
        if (ks < 7){
          #pragma unroll
          for (int jtl = 0; jtl < 4; jtl++) bcur[jtl] = bnxt[jtl];
        }
      }
      __syncthreads();   // all reads of h done before overwrite

      #pragma unroll
      for (int jtl = 0; jtl < 4; jtl++){
        int j = (wave * 4 + jtl) * 16 + col;       // D: col = lane&15
        float bb = bp[k * 256 + j];
        #pragma unroll
        for (int mt = 0; mt < 4; mt++){
          #pragma unroll
          for (int r = 0; r < 4; r++){
            int m = mt * 16 + quad * 4 + r;        // D: row = quad*4 + r
            lds_h[swz(m, j)] = f2bf(fast_tanh(acc[mt][jtl][r] + bb));
          }
        }
      }
      __syncthreads();
    }

    // ---- layer 3 (256 -> 1) + window-weighted scatter ----
    {
      int m = t >> 2, q = t & 3;     // 4 threads per point
      float dot = 0.f;
      #pragma unroll
      for (int cc = 0; cc < 8; cc++){
        int ci  = q * 8 + cc;
        int pos = ci ^ (m & 7);
        short8 hv = *(const short8*)&lds_h[m * 256 + pos * 8];
        #pragma unroll
        for (int jj = 0; jj < 8; jj++)
          dot = fmaf(bf2f(hv[jj]), s_w3[ci * 8 + jj], dot);
      }
      dot += __shfl_xor(dot, 1);
      dot += __shfl_xor(dot, 2);
      if (q == 0 && s_win[m] != 0.f)
        atomicAdd(&out[s_pidx[m]], s_win[m] * (dot + b3[k]));
    }
  }
}

extern "C" void kernel_launch(void* const* d_in, const int* in_sizes, int n_in,
                              void* d_out, int out_size, void* d_ws, size_t ws_size,
                              hipStream_t stream){
  const float* x     = (const float*)d_in[0];
  const float* W0    = (const float*)d_in[1];
  const float* b0    = (const float*)d_in[2];
  const float* W1    = (const float*)d_in[3];
  const float* b1    = (const float*)d_in[4];
  const float* W2    = (const float*)d_in[5];
  const float* b2    = (const float*)d_in[6];
  const float* W3    = (const float*)d_in[7];
  const float* b3    = (const float*)d_in[8];
  const float* xmins = (const float*)d_in[9];
  const float* xmaxs = (const float*)d_in[10];
  float* out = (float*)d_out;

  char* ws = (char*)d_ws;                     // needs ~6.3 MB
  short*         wsw   = (short*)        (ws + WS_W);
  unsigned char* cnt8  = (unsigned char*)(ws + WS_CNT);
  int*           ilist = (int*)          (ws + WS_ILIST);
  float*         wlist = (float*)        (ws + WS_WLIST);

  prep_fused<<<1088, 256, 0, stream>>>(W1, W2, x, xmins, xmaxs,
                                       wsw, cnt8, ilist, wlist, out);
  fbpinn_main<<<1024, 256, 0, stream>>>(x, W0, b0, b1, b2, W3, b3, xmins, xmaxs,
                                        wsw, (const unsigned int*)cnt8,
                                        ilist, wlist, out);
}